// Round 1
// baseline (24269.037 us; speedup 1.0000x reference)
//
#include <hip/hip_runtime.h>

// LureSystem recurrence, MI355X.
// R2: 4-way K-split at 1024 threads. Each thread holds a QUARTER row (64 cols)
// of C2/A/B2 as packed f16 => 96 weight VGPRs (was 192). Fits the 128-VGPR
// tier cleanly -> no spills AND 4 waves/EU (16 waves/CU, 2x occupancy vs R1's
// waves_per_eu(2,2) config). Same total VALU/LDS work; reductions 4-way.

#define NSTEP 2048

typedef _Float16 half_t;
typedef _Float16 half2_t __attribute__((ext_vector_type(2)));

__device__ __forceinline__ float fdot2(half2_t a, half2_t b, float c) {
    return __builtin_amdgcn_fdot2(a, b, c, false);
}

union F4H { float4 f; half2_t h[4]; };
union F2H { float2 f; half2_t h[2]; };

__device__ __forceinline__ float tanh_fast(float p) {
    float ex = __expf(2.0f * p);
    return 1.0f - 2.0f / (ex + 1.0f);
}

// LDS layout (bytes):
//      0: D21T4  [16 j4][256 i][4h]  32768
//  32768: BT4    [16 j4][256 i][4h]  32768
//  65536: CT4    [64 j4][ 64 i][4h]  32768
//  98304: D12T4  [64 j4][ 64 i][4h]  32768
// 131072: DT4    [16 j4][ 64 i][4h]   8192
// 139264: x_h    [256] half            512
// 139776: w_h    [256] half            512
// 140288: d_h    [2][64] half          256
// 140544: red_a  [1024] float         4096
// 144640: red_e  [1024] float         4096
// total 148736 B  (<= 160 KiB, 1 block/CU)
#define LDS_TOTAL 148736

__global__
__attribute__((amdgpu_flat_work_group_size(1024, 1024)))
__attribute__((amdgpu_waves_per_eu(4, 4)))
void lure_kernel(const float* __restrict__ d_g, const float* __restrict__ x0_g,
                 const float* __restrict__ A_g, const float* __restrict__ B_g,
                 const float* __restrict__ B2_g, const float* __restrict__ C_g,
                 const float* __restrict__ D_g, const float* __restrict__ D12_g,
                 const float* __restrict__ C2_g, const float* __restrict__ D21_g,
                 float* __restrict__ out)
{
    extern __shared__ char smem[];
    half_t* D21T = (half_t*)(smem + 0);
    half_t* BT   = (half_t*)(smem + 32768);
    half_t* CT   = (half_t*)(smem + 65536);
    half_t* D12T = (half_t*)(smem + 98304);
    half_t* DT   = (half_t*)(smem + 131072);
    half_t* x_h  = (half_t*)(smem + 139264);
    half_t* w_h  = (half_t*)(smem + 139776);
    half_t* d_h  = (half_t*)(smem + 140288);
    float*  red_a= (float*)(smem + 140544);
    float*  red_e= (float*)(smem + 144640);

    const int t = threadIdx.x;
    const int b = blockIdx.x;
    const int i = t & 255;    // output row for w/x phases
    const int q = t >> 8;     // K-quarter (cols 64q .. 64q+63)
    const int ie = t & 63;    // output row for e phase
    const int sl = t >> 6;    // e-phase K slice (16 slices)

    // ---- one-time: register-resident quarter-row slices of C2, A, B2
    half2_t c2r[32], ar[32], b2r[32];
    {
        const float4* c2p = (const float4*)(C2_g + i * 256 + q * 64);
#pragma unroll
        for (int u = 0; u < 16; ++u) {
            float4 v = c2p[u];
            c2r[2*u]   = half2_t{(half_t)v.x, (half_t)v.y};
            c2r[2*u+1] = half2_t{(half_t)v.z, (half_t)v.w};
        }
        const float4* ap = (const float4*)(A_g + i * 256 + q * 64);
#pragma unroll
        for (int u = 0; u < 16; ++u) {
            float4 v = ap[u];
            ar[2*u]    = half2_t{(half_t)v.x, (half_t)v.y};
            ar[2*u+1]  = half2_t{(half_t)v.z, (half_t)v.w};
        }
        const float4* b2p = (const float4*)(B2_g + i * 256 + q * 64);
#pragma unroll
        for (int u = 0; u < 16; ++u) {
            float4 v = b2p[u];
            b2r[2*u]   = half2_t{(half_t)v.x, (half_t)v.y};
            b2r[2*u+1] = half2_t{(half_t)v.z, (half_t)v.w};
        }
    }

    // ---- one-time: LDS transposed-packed small matrices
    for (int e = t; e < 256 * 64; e += 1024) {         // D21 [256][64]
        int r = e >> 6, c = e & 63;
        D21T[((c >> 2) * 256 + r) * 4 + (c & 3)] = (half_t)D21_g[e];
    }
    for (int e = t; e < 256 * 64; e += 1024) {         // B [256][64]
        int r = e >> 6, c = e & 63;
        BT[((c >> 2) * 256 + r) * 4 + (c & 3)] = (half_t)B_g[e];
    }
    for (int e = t; e < 64 * 256; e += 1024) {         // C [64][256]
        int r = e >> 8, c = e & 255;
        CT[((c >> 2) * 64 + r) * 4 + (c & 3)] = (half_t)C_g[e];
    }
    for (int e = t; e < 64 * 256; e += 1024) {         // D12 [64][256]
        int r = e >> 8, c = e & 255;
        D12T[((c >> 2) * 64 + r) * 4 + (c & 3)] = (half_t)D12_g[e];
    }
    for (int e = t; e < 64 * 64; e += 1024) {          // D [64][64]
        int r = e >> 6, c = e & 63;
        DT[((c >> 2) * 64 + r) * 4 + (c & 3)] = (half_t)D_g[e];
    }
    // initial state + d_0
    if (t < 256) x_h[t] = (half_t)x0_g[b * 256 + t];
    if (t >= 320 && t < 384) d_h[t - 320] = (half_t)d_g[(b * NSTEP) * 64 + (t - 320)];
    __syncthreads();

    const float* dpre = d_g + (b * NSTEP + 1) * 64 + (t - 320); // wave 5 prefetch ptr
    const int out_e_base = b * (NSTEP * 64);
    const int out_x_base = 256 * NSTEP * 64 + b * 256;
    const int out_w_base = 256 * NSTEP * 64 + 256 * 256 + b * 256;

    int cur = 0; // d ring slot for d_k (== k & 1)
    for (int k = 0; k <= NSTEP; ++k) {
        const bool live = (k < NSTEP);

        // prefetch d_{k+1} (wave 5)
        float dpf = 0.0f;
        if (k < NSTEP - 1 && t >= 320 && t < 384) dpf = *dpre;

        // ---- R1: w_pre partial (C2·x + D21·d) and A·x partial
        float aC0 = 0.f, aC1 = 0.f, aA0 = 0.f, aA1 = 0.f;
        if (live) {
            const half_t* xs = x_h + (q << 6);
#pragma unroll
            for (int cc = 0; cc < 8; ++cc) {
                F4H xv; xv.f = *(const float4*)(xs + cc * 8);
                aC0 = fdot2(c2r[4*cc+0], xv.h[0], aC0);
                aA0 = fdot2(ar [4*cc+0], xv.h[0], aA0);
                aC1 = fdot2(c2r[4*cc+1], xv.h[1], aC1);
                aA1 = fdot2(ar [4*cc+1], xv.h[1], aA1);
                aC0 = fdot2(c2r[4*cc+2], xv.h[2], aC0);
                aA0 = fdot2(ar [4*cc+2], xv.h[2], aA0);
                aC1 = fdot2(c2r[4*cc+3], xv.h[3], aC1);
                aA1 = fdot2(ar [4*cc+3], xv.h[3], aA1);
            }
#pragma unroll
            for (int qq = 0; qq < 4; ++qq) {
                int j4 = (q << 2) + qq;
                F2H m;  m.f  = *(const float2*)(D21T + (j4 * 256 + i) * 4);
                F2H dv; dv.f = *(const float2*)(d_h + cur * 64 + (j4 << 2));
                aC0 = fdot2(m.h[0], dv.h[0], aC0);
                aC1 = fdot2(m.h[1], dv.h[1], aC1);
            }
            red_a[t] = aC0 + aC1;
        }

        // ---- E phase for step k-1: e = C·x_k + D12·w_{k-1} + D·d_{k-1}
        if (k > 0) {
            float aE0 = 0.f, aE1 = 0.f;
#pragma unroll
            for (int qq = 0; qq < 4; ++qq) {
                int j4 = (sl << 2) + qq;
                F2H m;  m.f  = *(const float2*)(CT + (j4 * 64 + ie) * 4);
                F2H xv; xv.f = *(const float2*)(x_h + (j4 << 2));
                aE0 = fdot2(m.h[0], xv.h[0], aE0);
                aE1 = fdot2(m.h[1], xv.h[1], aE1);
            }
#pragma unroll
            for (int qq = 0; qq < 4; ++qq) {
                int j4 = (sl << 2) + qq;
                F2H m;  m.f  = *(const float2*)(D12T + (j4 * 64 + ie) * 4);
                F2H wv; wv.f = *(const float2*)(w_h + (j4 << 2));
                aE0 = fdot2(m.h[0], wv.h[0], aE0);
                aE1 = fdot2(m.h[1], wv.h[1], aE1);
            }
            {
                int j4 = sl;
                F2H m;  m.f  = *(const float2*)(DT + (j4 * 64 + ie) * 4);
                F2H dv; dv.f = *(const float2*)(d_h + (cur ^ 1) * 64 + (j4 << 2));
                aE0 = fdot2(m.h[0], dv.h[0], aE0);
                aE1 = fdot2(m.h[1], dv.h[1], aE1);
            }
            red_e[t] = aE0 + aE1;
        }
        __syncthreads(); // A

        // ---- R2: tanh+w (waves 0-3) | e-reduce+store (wave 4) | d_h fill (wave 5)
        if (t < 256) {
            if (live) {
                float p = red_a[t] + red_a[t + 256] + red_a[t + 512] + red_a[t + 768];
                float wv = tanh_fast(p);
                w_h[t] = (half_t)wv;
                if (k == NSTEP - 1) out[out_w_base + t] = wv;
            }
        } else if (t < 320) {
            if (k > 0) {
                float ev = 0.f;
#pragma unroll
                for (int s = 0; s < 16; ++s) ev += red_e[ie + 64 * s];
                out[out_e_base + (k - 1) * 64 + ie] = ev;
            }
        } else if (t < 384) {
            if (k < NSTEP - 1) d_h[(cur ^ 1) * 64 + (t - 320)] = (half_t)dpf;
        }
        __syncthreads(); // B

        // ---- R3: x' partial (A·x done) + B2·w + B·d
        if (live) {
            float aX0 = aA0, aX1 = aA1;
            const half_t* wsl = w_h + (q << 6);
#pragma unroll
            for (int cc = 0; cc < 8; ++cc) {
                F4H wv; wv.f = *(const float4*)(wsl + cc * 8);
                aX0 = fdot2(b2r[4*cc+0], wv.h[0], aX0);
                aX1 = fdot2(b2r[4*cc+1], wv.h[1], aX1);
                aX0 = fdot2(b2r[4*cc+2], wv.h[2], aX0);
                aX1 = fdot2(b2r[4*cc+3], wv.h[3], aX1);
            }
#pragma unroll
            for (int qq = 0; qq < 4; ++qq) {
                int j4 = (q << 2) + qq;
                F2H m;  m.f  = *(const float2*)(BT + (j4 * 256 + i) * 4);
                F2H dv; dv.f = *(const float2*)(d_h + cur * 64 + (j4 << 2));
                aX0 = fdot2(m.h[0], dv.h[0], aX0);
                aX1 = fdot2(m.h[1], dv.h[1], aX1);
            }
            red_a[t] = aX0 + aX1;
        }
        __syncthreads(); // C

        // ---- R4: x update
        if (live && t < 256) {
            float xv = red_a[t] + red_a[t + 256] + red_a[t + 512] + red_a[t + 768];
            x_h[t] = (half_t)xv;
            if (k == NSTEP - 1) out[out_x_base + t] = xv;
        }
        dpre += 64;
        cur ^= 1;
        __syncthreads(); // D
    }
}

extern "C" void kernel_launch(void* const* d_in, const int* in_sizes, int n_in,
                              void* d_out, int out_size, void* d_ws, size_t ws_size,
                              hipStream_t stream) {
    (void)in_sizes; (void)n_in; (void)out_size; (void)d_ws; (void)ws_size;
    const float* d_  = (const float*)d_in[0];
    const float* x0  = (const float*)d_in[1];
    const float* A   = (const float*)d_in[2];
    const float* B   = (const float*)d_in[3];
    const float* B2  = (const float*)d_in[4];
    const float* C   = (const float*)d_in[5];
    const float* D   = (const float*)d_in[6];
    const float* D12 = (const float*)d_in[7];
    const float* C2  = (const float*)d_in[8];
    const float* D21 = (const float*)d_in[9];
    float* out = (float*)d_out;

    hipFuncSetAttribute((const void*)lure_kernel,
                        hipFuncAttributeMaxDynamicSharedMemorySize, LDS_TOTAL);
    hipLaunchKernelGGL(lure_kernel, dim3(256), dim3(1024), LDS_TOTAL, stream,
                       d_, x0, A, B, B2, C, D, D12, C2, D21, out);
}

// Round 2
// 23543.283 us; speedup vs baseline: 1.0308x; 1.0308x over previous
//
#include <hip/hip_runtime.h>

// LureSystem recurrence, MI355X.
// R3: STATIC LDS. R2's counters showed VGPR_Count=64 + 33.3 GB FETCH/dispatch
// = the allocator budgeted the 8-waves/EU tier (64 VGPRs) because dynamic
// extern __shared__ hid the 148 KB LDS footprint (which caps occupancy at
// 4 waves/SIMD). ~16 of the 96 packed weight VGPRs were spill-reloaded every
// step -> 62 B/thread/step -> the entire 24 ms runtime was remat traffic.
// Static LDS lets the backend see occupancy = 4 waves/EU -> 128-VGPR budget.
// amdgpu_num_vgpr(128) caps allocation so the 16-wave workgroup stays
// resident (4 waves/SIMD x 128 = 512 = full RF).

#define NSTEP 2048

typedef _Float16 half_t;
typedef _Float16 half2_t __attribute__((ext_vector_type(2)));

__device__ __forceinline__ float fdot2(half2_t a, half2_t b, float c) {
    return __builtin_amdgcn_fdot2(a, b, c, false);
}

union F4H { float4 f; half2_t h[4]; };
union F2H { float2 f; half2_t h[2]; };

__device__ __forceinline__ float tanh_fast(float p) {
    float ex = __expf(2.0f * p);
    return 1.0f - 2.0f / (ex + 1.0f);
}

// LDS layout (bytes):
//      0: D21T4  [16 j4][256 i][4h]  32768
//  32768: BT4    [16 j4][256 i][4h]  32768
//  65536: CT4    [64 j4][ 64 i][4h]  32768
//  98304: D12T4  [64 j4][ 64 i][4h]  32768
// 131072: DT4    [16 j4][ 64 i][4h]   8192
// 139264: x_h    [256] half            512
// 139776: w_h    [256] half            512
// 140288: d_h    [2][64] half          256
// 140544: red_a  [1024] float         4096
// 144640: red_e  [1024] float         4096
// total 148736 B  (<= 160 KiB addressable on gfx950, 1 block/CU)
#define LDS_TOTAL 148736

__global__
__attribute__((amdgpu_flat_work_group_size(1024, 1024)))
__attribute__((amdgpu_waves_per_eu(4, 4)))
__attribute__((amdgpu_num_vgpr(128)))
void lure_kernel(const float* __restrict__ d_g, const float* __restrict__ x0_g,
                 const float* __restrict__ A_g, const float* __restrict__ B_g,
                 const float* __restrict__ B2_g, const float* __restrict__ C_g,
                 const float* __restrict__ D_g, const float* __restrict__ D12_g,
                 const float* __restrict__ C2_g, const float* __restrict__ D21_g,
                 float* __restrict__ out)
{
    __shared__ __align__(16) char smem[LDS_TOTAL];
    half_t* D21T = (half_t*)(smem + 0);
    half_t* BT   = (half_t*)(smem + 32768);
    half_t* CT   = (half_t*)(smem + 65536);
    half_t* D12T = (half_t*)(smem + 98304);
    half_t* DT   = (half_t*)(smem + 131072);
    half_t* x_h  = (half_t*)(smem + 139264);
    half_t* w_h  = (half_t*)(smem + 139776);
    half_t* d_h  = (half_t*)(smem + 140288);
    float*  red_a= (float*)(smem + 140544);
    float*  red_e= (float*)(smem + 144640);

    const int t = threadIdx.x;
    const int b = blockIdx.x;
    const int i = t & 255;    // output row for w/x phases
    const int q = t >> 8;     // K-quarter (cols 64q .. 64q+63)
    const int ie = t & 63;    // output row for e phase
    const int sl = t >> 6;    // e-phase K slice (16 slices)

    // ---- one-time: register-resident quarter-row slices of C2, A, B2
    half2_t c2r[32], ar[32], b2r[32];
    {
        const float4* c2p = (const float4*)(C2_g + i * 256 + q * 64);
#pragma unroll
        for (int u = 0; u < 16; ++u) {
            float4 v = c2p[u];
            c2r[2*u]   = half2_t{(half_t)v.x, (half_t)v.y};
            c2r[2*u+1] = half2_t{(half_t)v.z, (half_t)v.w};
        }
        const float4* ap = (const float4*)(A_g + i * 256 + q * 64);
#pragma unroll
        for (int u = 0; u < 16; ++u) {
            float4 v = ap[u];
            ar[2*u]    = half2_t{(half_t)v.x, (half_t)v.y};
            ar[2*u+1]  = half2_t{(half_t)v.z, (half_t)v.w};
        }
        const float4* b2p = (const float4*)(B2_g + i * 256 + q * 64);
#pragma unroll
        for (int u = 0; u < 16; ++u) {
            float4 v = b2p[u];
            b2r[2*u]   = half2_t{(half_t)v.x, (half_t)v.y};
            b2r[2*u+1] = half2_t{(half_t)v.z, (half_t)v.w};
        }
    }

    // ---- one-time: LDS transposed-packed small matrices
    for (int e = t; e < 256 * 64; e += 1024) {         // D21 [256][64]
        int r = e >> 6, c = e & 63;
        D21T[((c >> 2) * 256 + r) * 4 + (c & 3)] = (half_t)D21_g[e];
    }
    for (int e = t; e < 256 * 64; e += 1024) {         // B [256][64]
        int r = e >> 6, c = e & 63;
        BT[((c >> 2) * 256 + r) * 4 + (c & 3)] = (half_t)B_g[e];
    }
    for (int e = t; e < 64 * 256; e += 1024) {         // C [64][256]
        int r = e >> 8, c = e & 255;
        CT[((c >> 2) * 64 + r) * 4 + (c & 3)] = (half_t)C_g[e];
    }
    for (int e = t; e < 64 * 256; e += 1024) {         // D12 [64][256]
        int r = e >> 8, c = e & 255;
        D12T[((c >> 2) * 64 + r) * 4 + (c & 3)] = (half_t)D12_g[e];
    }
    for (int e = t; e < 64 * 64; e += 1024) {          // D [64][64]
        int r = e >> 6, c = e & 63;
        DT[((c >> 2) * 64 + r) * 4 + (c & 3)] = (half_t)D_g[e];
    }
    // initial state + d_0
    if (t < 256) x_h[t] = (half_t)x0_g[b * 256 + t];
    if (t >= 320 && t < 384) d_h[t - 320] = (half_t)d_g[(b * NSTEP) * 64 + (t - 320)];
    __syncthreads();

    const float* dpre = d_g + (b * NSTEP + 1) * 64 + (t - 320); // wave 5 prefetch ptr
    const int out_e_base = b * (NSTEP * 64);
    const int out_x_base = 256 * NSTEP * 64 + b * 256;
    const int out_w_base = 256 * NSTEP * 64 + 256 * 256 + b * 256;

    int cur = 0; // d ring slot for d_k (== k & 1)
    for (int k = 0; k <= NSTEP; ++k) {
        const bool live = (k < NSTEP);

        // prefetch d_{k+1} (wave 5)
        float dpf = 0.0f;
        if (k < NSTEP - 1 && t >= 320 && t < 384) dpf = *dpre;

        // ---- R1: w_pre partial (C2·x + D21·d) and A·x partial
        float aC0 = 0.f, aC1 = 0.f, aA0 = 0.f, aA1 = 0.f;
        if (live) {
            const half_t* xs = x_h + (q << 6);
#pragma unroll
            for (int cc = 0; cc < 8; ++cc) {
                F4H xv; xv.f = *(const float4*)(xs + cc * 8);
                aC0 = fdot2(c2r[4*cc+0], xv.h[0], aC0);
                aA0 = fdot2(ar [4*cc+0], xv.h[0], aA0);
                aC1 = fdot2(c2r[4*cc+1], xv.h[1], aC1);
                aA1 = fdot2(ar [4*cc+1], xv.h[1], aA1);
                aC0 = fdot2(c2r[4*cc+2], xv.h[2], aC0);
                aA0 = fdot2(ar [4*cc+2], xv.h[2], aA0);
                aC1 = fdot2(c2r[4*cc+3], xv.h[3], aC1);
                aA1 = fdot2(ar [4*cc+3], xv.h[3], aA1);
            }
#pragma unroll
            for (int qq = 0; qq < 4; ++qq) {
                int j4 = (q << 2) + qq;
                F2H m;  m.f  = *(const float2*)(D21T + (j4 * 256 + i) * 4);
                F2H dv; dv.f = *(const float2*)(d_h + cur * 64 + (j4 << 2));
                aC0 = fdot2(m.h[0], dv.h[0], aC0);
                aC1 = fdot2(m.h[1], dv.h[1], aC1);
            }
            red_a[t] = aC0 + aC1;
        }

        // ---- E phase for step k-1: e = C·x_k + D12·w_{k-1} + D·d_{k-1}
        if (k > 0) {
            float aE0 = 0.f, aE1 = 0.f;
#pragma unroll
            for (int qq = 0; qq < 4; ++qq) {
                int j4 = (sl << 2) + qq;
                F2H m;  m.f  = *(const float2*)(CT + (j4 * 64 + ie) * 4);
                F2H xv; xv.f = *(const float2*)(x_h + (j4 << 2));
                aE0 = fdot2(m.h[0], xv.h[0], aE0);
                aE1 = fdot2(m.h[1], xv.h[1], aE1);
            }
#pragma unroll
            for (int qq = 0; qq < 4; ++qq) {
                int j4 = (sl << 2) + qq;
                F2H m;  m.f  = *(const float2*)(D12T + (j4 * 64 + ie) * 4);
                F2H wv; wv.f = *(const float2*)(w_h + (j4 << 2));
                aE0 = fdot2(m.h[0], wv.h[0], aE0);
                aE1 = fdot2(m.h[1], wv.h[1], aE1);
            }
            {
                int j4 = sl;
                F2H m;  m.f  = *(const float2*)(DT + (j4 * 64 + ie) * 4);
                F2H dv; dv.f = *(const float2*)(d_h + (cur ^ 1) * 64 + (j4 << 2));
                aE0 = fdot2(m.h[0], dv.h[0], aE0);
                aE1 = fdot2(m.h[1], dv.h[1], aE1);
            }
            red_e[t] = aE0 + aE1;
        }
        __syncthreads(); // A

        // ---- R2: tanh+w (waves 0-3) | e-reduce+store (wave 4) | d_h fill (wave 5)
        if (t < 256) {
            if (live) {
                float p = red_a[t] + red_a[t + 256] + red_a[t + 512] + red_a[t + 768];
                float wv = tanh_fast(p);
                w_h[t] = (half_t)wv;
                if (k == NSTEP - 1) out[out_w_base + t] = wv;
            }
        } else if (t < 320) {
            if (k > 0) {
                float ev = 0.f;
#pragma unroll
                for (int s = 0; s < 16; ++s) ev += red_e[ie + 64 * s];
                out[out_e_base + (k - 1) * 64 + ie] = ev;
            }
        } else if (t < 384) {
            if (k < NSTEP - 1) d_h[(cur ^ 1) * 64 + (t - 320)] = (half_t)dpf;
        }
        __syncthreads(); // B

        // ---- R3: x' partial (A·x done) + B2·w + B·d
        if (live) {
            float aX0 = aA0, aX1 = aA1;
            const half_t* wsl = w_h + (q << 6);
#pragma unroll
            for (int cc = 0; cc < 8; ++cc) {
                F4H wv; wv.f = *(const float4*)(wsl + cc * 8);
                aX0 = fdot2(b2r[4*cc+0], wv.h[0], aX0);
                aX1 = fdot2(b2r[4*cc+1], wv.h[1], aX1);
                aX0 = fdot2(b2r[4*cc+2], wv.h[2], aX0);
                aX1 = fdot2(b2r[4*cc+3], wv.h[3], aX1);
            }
#pragma unroll
            for (int qq = 0; qq < 4; ++qq) {
                int j4 = (q << 2) + qq;
                F2H m;  m.f  = *(const float2*)(BT + (j4 * 256 + i) * 4);
                F2H dv; dv.f = *(const float2*)(d_h + cur * 64 + (j4 << 2));
                aX0 = fdot2(m.h[0], dv.h[0], aX0);
                aX1 = fdot2(m.h[1], dv.h[1], aX1);
            }
            red_a[t] = aX0 + aX1;
        }
        __syncthreads(); // C

        // ---- R4: x update
        if (live && t < 256) {
            float xv = red_a[t] + red_a[t + 256] + red_a[t + 512] + red_a[t + 768];
            x_h[t] = (half_t)xv;
            if (k == NSTEP - 1) out[out_x_base + t] = xv;
        }
        dpre += 64;
        cur ^= 1;
        __syncthreads(); // D
    }
}

extern "C" void kernel_launch(void* const* d_in, const int* in_sizes, int n_in,
                              void* d_out, int out_size, void* d_ws, size_t ws_size,
                              hipStream_t stream) {
    (void)in_sizes; (void)n_in; (void)out_size; (void)d_ws; (void)ws_size;
    const float* d_  = (const float*)d_in[0];
    const float* x0  = (const float*)d_in[1];
    const float* A   = (const float*)d_in[2];
    const float* B   = (const float*)d_in[3];
    const float* B2  = (const float*)d_in[4];
    const float* C   = (const float*)d_in[5];
    const float* D   = (const float*)d_in[6];
    const float* D12 = (const float*)d_in[7];
    const float* C2  = (const float*)d_in[8];
    const float* D21 = (const float*)d_in[9];
    float* out = (float*)d_out;

    hipLaunchKernelGGL(lure_kernel, dim3(256), dim3(1024), 0, stream,
                       d_, x0, A, B, B2, C, D, D12, C2, D21, out);
}

// Round 4
// 23449.191 us; speedup vs baseline: 1.0350x; 1.0040x over previous
//
#include <hip/hip_runtime.h>

// LureSystem recurrence, MI355X.
// R4: weights as ext_vector SSA values. R2/R3 counters (VGPR=64, 33.6 GB
// read-only FETCH = 62 B/thread/step private scratch reload, VALUBusy 9.5%)
// showed the half2 c2r[32]/ar[32]/b2r[32] LOCAL ARRAYS were never promoted:
// SROA runs before full unrolling, sees variable indices, leaves the allocas
// in scratch -> every weight element re-read from HBM every step. Fix: hold
// each 64-col weight slice as 2x uint16-wide ext_vector values (single SSA
// values, 16 VGPRs each, promoted unconditionally; element access is
// constant-index extractelement after the loops are split v0/v1).
// 96 weight VGPRs + ~20 temps fits the 128-VGPR budget of
// __launch_bounds__(1024, 4) (16-wave workgroup => hard cap 128).

#define NSTEP 2048

typedef _Float16 half_t;
typedef _Float16 half2_t __attribute__((ext_vector_type(2)));
typedef unsigned int uint16v __attribute__((ext_vector_type(16)));

__device__ __forceinline__ float fdot2(half2_t a, half2_t b, float c) {
    return __builtin_amdgcn_fdot2(a, b, c, false);
}

__device__ __forceinline__ unsigned int packh2(float x, float y) {
    union { half2_t h; unsigned int u; } c;
    c.h = half2_t{(half_t)x, (half_t)y};
    return c.u;
}

__device__ __forceinline__ half2_t h2(unsigned int u) {
    union { unsigned int x; half2_t h; } c;
    c.x = u;
    return c.h;
}

union F4H { float4 f; half2_t h[4]; };
union F2H { float2 f; half2_t h[2]; };

__device__ __forceinline__ float tanh_fast(float p) {
    float ex = __expf(2.0f * p);
    return 1.0f - 2.0f / (ex + 1.0f);
}

// LDS layout (bytes):
//      0: D21T4  [16 j4][256 i][4h]  32768
//  32768: BT4    [16 j4][256 i][4h]  32768
//  65536: CT4    [64 j4][ 64 i][4h]  32768
//  98304: D12T4  [64 j4][ 64 i][4h]  32768
// 131072: DT4    [16 j4][ 64 i][4h]   8192
// 139264: x_h    [256] half            512
// 139776: w_h    [256] half            512
// 140288: d_h    [2][64] half          256
// 140544: red_a  [1024] float         4096
// 144640: red_e  [1024] float         4096
// total 148736 B  (<= 160 KiB, 1 block/CU)
#define LDS_TOTAL 148736

__global__
__launch_bounds__(1024, 4)
void lure_kernel(const float* __restrict__ d_g, const float* __restrict__ x0_g,
                 const float* __restrict__ A_g, const float* __restrict__ B_g,
                 const float* __restrict__ B2_g, const float* __restrict__ C_g,
                 const float* __restrict__ D_g, const float* __restrict__ D12_g,
                 const float* __restrict__ C2_g, const float* __restrict__ D21_g,
                 float* __restrict__ out)
{
    __shared__ __align__(16) char smem[LDS_TOTAL];
    half_t* D21T = (half_t*)(smem + 0);
    half_t* BT   = (half_t*)(smem + 32768);
    half_t* CT   = (half_t*)(smem + 65536);
    half_t* D12T = (half_t*)(smem + 98304);
    half_t* DT   = (half_t*)(smem + 131072);
    half_t* x_h  = (half_t*)(smem + 139264);
    half_t* w_h  = (half_t*)(smem + 139776);
    half_t* d_h  = (half_t*)(smem + 140288);
    float*  red_a= (float*)(smem + 140544);
    float*  red_e= (float*)(smem + 144640);

    const int t = threadIdx.x;
    const int b = blockIdx.x;
    const int i = t & 255;    // output row for w/x phases
    const int q = t >> 8;     // K-quarter (cols 64q .. 64q+63)
    const int ie = t & 63;    // output row for e phase
    const int sl = t >> 6;    // e-phase K slice (16 slices)

    // ---- one-time: register-resident quarter-row slices of C2, A, B2
    // Each slice: 64 cols = 32 packed half2 = 2x uint16v SSA values.
    uint16v c2v0 = {}, c2v1 = {}, av0 = {}, av1 = {}, b2v0 = {}, b2v1 = {};
    {
        const float4* c2p = (const float4*)(C2_g + i * 256 + q * 64);
#pragma unroll
        for (int u = 0; u < 8; ++u) {
            float4 v = c2p[u];
            c2v0[2*u]   = packh2(v.x, v.y);
            c2v0[2*u+1] = packh2(v.z, v.w);
        }
#pragma unroll
        for (int u = 0; u < 8; ++u) {
            float4 v = c2p[8 + u];
            c2v1[2*u]   = packh2(v.x, v.y);
            c2v1[2*u+1] = packh2(v.z, v.w);
        }
        const float4* ap = (const float4*)(A_g + i * 256 + q * 64);
#pragma unroll
        for (int u = 0; u < 8; ++u) {
            float4 v = ap[u];
            av0[2*u]   = packh2(v.x, v.y);
            av0[2*u+1] = packh2(v.z, v.w);
        }
#pragma unroll
        for (int u = 0; u < 8; ++u) {
            float4 v = ap[8 + u];
            av1[2*u]   = packh2(v.x, v.y);
            av1[2*u+1] = packh2(v.z, v.w);
        }
        const float4* b2p = (const float4*)(B2_g + i * 256 + q * 64);
#pragma unroll
        for (int u = 0; u < 8; ++u) {
            float4 v = b2p[u];
            b2v0[2*u]   = packh2(v.x, v.y);
            b2v0[2*u+1] = packh2(v.z, v.w);
        }
#pragma unroll
        for (int u = 0; u < 8; ++u) {
            float4 v = b2p[8 + u];
            b2v1[2*u]   = packh2(v.x, v.y);
            b2v1[2*u+1] = packh2(v.z, v.w);
        }
    }

    // ---- one-time: LDS transposed-packed small matrices
    for (int e = t; e < 256 * 64; e += 1024) {         // D21 [256][64]
        int r = e >> 6, c = e & 63;
        D21T[((c >> 2) * 256 + r) * 4 + (c & 3)] = (half_t)D21_g[e];
    }
    for (int e = t; e < 256 * 64; e += 1024) {         // B [256][64]
        int r = e >> 6, c = e & 63;
        BT[((c >> 2) * 256 + r) * 4 + (c & 3)] = (half_t)B_g[e];
    }
    for (int e = t; e < 64 * 256; e += 1024) {         // C [64][256]
        int r = e >> 8, c = e & 255;
        CT[((c >> 2) * 64 + r) * 4 + (c & 3)] = (half_t)C_g[e];
    }
    for (int e = t; e < 64 * 256; e += 1024) {         // D12 [64][256]
        int r = e >> 8, c = e & 255;
        D12T[((c >> 2) * 64 + r) * 4 + (c & 3)] = (half_t)D12_g[e];
    }
    for (int e = t; e < 64 * 64; e += 1024) {          // D [64][64]
        int r = e >> 6, c = e & 63;
        DT[((c >> 2) * 64 + r) * 4 + (c & 3)] = (half_t)D_g[e];
    }
    // initial state + d_0
    if (t < 256) x_h[t] = (half_t)x0_g[b * 256 + t];
    if (t >= 320 && t < 384) d_h[t - 320] = (half_t)d_g[(b * NSTEP) * 64 + (t - 320)];
    __syncthreads();

    const float* dpre = d_g + (b * NSTEP + 1) * 64 + (t - 320); // wave 5 prefetch ptr
    const int out_e_base = b * (NSTEP * 64);
    const int out_x_base = 256 * NSTEP * 64 + b * 256;
    const int out_w_base = 256 * NSTEP * 64 + 256 * 256 + b * 256;

    int cur = 0; // d ring slot for d_k (== k & 1)
    for (int k = 0; k <= NSTEP; ++k) {
        const bool live = (k < NSTEP);

        // prefetch d_{k+1} (wave 5)
        float dpf = 0.0f;
        if (k < NSTEP - 1 && t >= 320 && t < 384) dpf = *dpre;

        // ---- R1: w_pre partial (C2·x + D21·d) and A·x partial
        float aC0 = 0.f, aC1 = 0.f, aA0 = 0.f, aA1 = 0.f;
        if (live) {
            const half_t* xs = x_h + (q << 6);
#pragma unroll
            for (int cc = 0; cc < 4; ++cc) {           // cols 0..31 of slice
                F4H xv; xv.f = *(const float4*)(xs + cc * 8);
                aC0 = fdot2(h2(c2v0[4*cc+0]), xv.h[0], aC0);
                aA0 = fdot2(h2(av0 [4*cc+0]), xv.h[0], aA0);
                aC1 = fdot2(h2(c2v0[4*cc+1]), xv.h[1], aC1);
                aA1 = fdot2(h2(av0 [4*cc+1]), xv.h[1], aA1);
                aC0 = fdot2(h2(c2v0[4*cc+2]), xv.h[2], aC0);
                aA0 = fdot2(h2(av0 [4*cc+2]), xv.h[2], aA0);
                aC1 = fdot2(h2(c2v0[4*cc+3]), xv.h[3], aC1);
                aA1 = fdot2(h2(av0 [4*cc+3]), xv.h[3], aA1);
            }
#pragma unroll
            for (int cc = 0; cc < 4; ++cc) {           // cols 32..63 of slice
                F4H xv; xv.f = *(const float4*)(xs + 32 + cc * 8);
                aC0 = fdot2(h2(c2v1[4*cc+0]), xv.h[0], aC0);
                aA0 = fdot2(h2(av1 [4*cc+0]), xv.h[0], aA0);
                aC1 = fdot2(h2(c2v1[4*cc+1]), xv.h[1], aC1);
                aA1 = fdot2(h2(av1 [4*cc+1]), xv.h[1], aA1);
                aC0 = fdot2(h2(c2v1[4*cc+2]), xv.h[2], aC0);
                aA0 = fdot2(h2(av1 [4*cc+2]), xv.h[2], aA0);
                aC1 = fdot2(h2(c2v1[4*cc+3]), xv.h[3], aC1);
                aA1 = fdot2(h2(av1 [4*cc+3]), xv.h[3], aA1);
            }
#pragma unroll
            for (int qq = 0; qq < 4; ++qq) {
                int j4 = (q << 2) + qq;
                F2H m;  m.f  = *(const float2*)(D21T + (j4 * 256 + i) * 4);
                F2H dv; dv.f = *(const float2*)(d_h + cur * 64 + (j4 << 2));
                aC0 = fdot2(m.h[0], dv.h[0], aC0);
                aC1 = fdot2(m.h[1], dv.h[1], aC1);
            }
            red_a[t] = aC0 + aC1;
        }

        // ---- E phase for step k-1: e = C·x_k + D12·w_{k-1} + D·d_{k-1}
        if (k > 0) {
            float aE0 = 0.f, aE1 = 0.f;
#pragma unroll
            for (int qq = 0; qq < 4; ++qq) {
                int j4 = (sl << 2) + qq;
                F2H m;  m.f  = *(const float2*)(CT + (j4 * 64 + ie) * 4);
                F2H xv; xv.f = *(const float2*)(x_h + (j4 << 2));
                aE0 = fdot2(m.h[0], xv.h[0], aE0);
                aE1 = fdot2(m.h[1], xv.h[1], aE1);
            }
#pragma unroll
            for (int qq = 0; qq < 4; ++qq) {
                int j4 = (sl << 2) + qq;
                F2H m;  m.f  = *(const float2*)(D12T + (j4 * 64 + ie) * 4);
                F2H wv; wv.f = *(const float2*)(w_h + (j4 << 2));
                aE0 = fdot2(m.h[0], wv.h[0], aE0);
                aE1 = fdot2(m.h[1], wv.h[1], aE1);
            }
            {
                int j4 = sl;
                F2H m;  m.f  = *(const float2*)(DT + (j4 * 64 + ie) * 4);
                F2H dv; dv.f = *(const float2*)(d_h + (cur ^ 1) * 64 + (j4 << 2));
                aE0 = fdot2(m.h[0], dv.h[0], aE0);
                aE1 = fdot2(m.h[1], dv.h[1], aE1);
            }
            red_e[t] = aE0 + aE1;
        }
        __syncthreads(); // A

        // ---- R2: tanh+w (waves 0-3) | e-reduce+store (wave 4) | d_h fill (wave 5)
        if (t < 256) {
            if (live) {
                float p = red_a[t] + red_a[t + 256] + red_a[t + 512] + red_a[t + 768];
                float wv = tanh_fast(p);
                w_h[t] = (half_t)wv;
                if (k == NSTEP - 1) out[out_w_base + t] = wv;
            }
        } else if (t < 320) {
            if (k > 0) {
                float ev = 0.f;
#pragma unroll
                for (int s = 0; s < 16; ++s) ev += red_e[ie + 64 * s];
                out[out_e_base + (k - 1) * 64 + ie] = ev;
            }
        } else if (t < 384) {
            if (k < NSTEP - 1) d_h[(cur ^ 1) * 64 + (t - 320)] = (half_t)dpf;
        }
        __syncthreads(); // B

        // ---- R3: x' partial (A·x done) + B2·w + B·d
        if (live) {
            float aX0 = aA0, aX1 = aA1;
            const half_t* wsl = w_h + (q << 6);
#pragma unroll
            for (int cc = 0; cc < 4; ++cc) {           // cols 0..31
                F4H wv; wv.f = *(const float4*)(wsl + cc * 8);
                aX0 = fdot2(h2(b2v0[4*cc+0]), wv.h[0], aX0);
                aX1 = fdot2(h2(b2v0[4*cc+1]), wv.h[1], aX1);
                aX0 = fdot2(h2(b2v0[4*cc+2]), wv.h[2], aX0);
                aX1 = fdot2(h2(b2v0[4*cc+3]), wv.h[3], aX1);
            }
#pragma unroll
            for (int cc = 0; cc < 4; ++cc) {           // cols 32..63
                F4H wv; wv.f = *(const float4*)(wsl + 32 + cc * 8);
                aX0 = fdot2(h2(b2v1[4*cc+0]), wv.h[0], aX0);
                aX1 = fdot2(h2(b2v1[4*cc+1]), wv.h[1], aX1);
                aX0 = fdot2(h2(b2v1[4*cc+2]), wv.h[2], aX0);
                aX1 = fdot2(h2(b2v1[4*cc+3]), wv.h[3], aX1);
            }
#pragma unroll
            for (int qq = 0; qq < 4; ++qq) {
                int j4 = (q << 2) + qq;
                F2H m;  m.f  = *(const float2*)(BT + (j4 * 256 + i) * 4);
                F2H dv; dv.f = *(const float2*)(d_h + cur * 64 + (j4 << 2));
                aX0 = fdot2(m.h[0], dv.h[0], aX0);
                aX1 = fdot2(m.h[1], dv.h[1], aX1);
            }
            red_a[t] = aX0 + aX1;
        }
        __syncthreads(); // C

        // ---- R4: x update
        if (live && t < 256) {
            float xv = red_a[t] + red_a[t + 256] + red_a[t + 512] + red_a[t + 768];
            x_h[t] = (half_t)xv;
            if (k == NSTEP - 1) out[out_x_base + t] = xv;
        }
        dpre += 64;
        cur ^= 1;
        __syncthreads(); // D
    }
}

extern "C" void kernel_launch(void* const* d_in, const int* in_sizes, int n_in,
                              void* d_out, int out_size, void* d_ws, size_t ws_size,
                              hipStream_t stream) {
    (void)in_sizes; (void)n_in; (void)out_size; (void)d_ws; (void)ws_size;
    const float* d_  = (const float*)d_in[0];
    const float* x0  = (const float*)d_in[1];
    const float* A   = (const float*)d_in[2];
    const float* B   = (const float*)d_in[3];
    const float* B2  = (const float*)d_in[4];
    const float* C   = (const float*)d_in[5];
    const float* D   = (const float*)d_in[6];
    const float* D12 = (const float*)d_in[7];
    const float* C2  = (const float*)d_in[8];
    const float* D21 = (const float*)d_in[9];
    float* out = (float*)d_out;

    hipLaunchKernelGGL(lure_kernel, dim3(256), dim3(1024), 0, stream,
                       d_, x0, A, B, B2, C, D, D12, C2, D21, out);
}

// Round 6
// 23280.415 us; speedup vs baseline: 1.0425x; 1.0072x over previous
//
#include <hip/hip_runtime.h>

// LureSystem recurrence, MI355X.
// R5: budget attribution round. R4 proved the SSA-vector fix works (FETCH
// -33% once 1/3 of weights got promoted) but VGPR_Count stayed 64 -> the
// allocator budget is the binding constraint; ~2/3 of the 96 weight VGPRs
// still spill-reload from scratch every step (41 B/thread/step = 22 GB =
// entire runtime at ~1 TB/s L2-miss BW). Capacity math: big-3 weights
// (C2,A,B2 = 384 KB fp16/CU) only fit on-CU at the 128-VGPR tier.
// Suspect: __launch_bounds__(1024,4)'s 2nd arg read as min BLOCKS/CU
// (CUDA-style) -> 4 blk x 16 waves -> 8 waves/EU -> 64-VGPR budget = the
// exact observed value. This round: drop launch_bounds, use the amdgpu-
// native attributes (flat_work_group_size + waves_per_eu(4,4)) with STATIC
// LDS -- this combination has never actually been benched (R3/R5 died on
// GPU acquisition).

#define NSTEP 2048

typedef _Float16 half_t;
typedef _Float16 half2_t __attribute__((ext_vector_type(2)));
typedef unsigned int uint16v __attribute__((ext_vector_type(16)));

__device__ __forceinline__ float fdot2(half2_t a, half2_t b, float c) {
    return __builtin_amdgcn_fdot2(a, b, c, false);
}

__device__ __forceinline__ unsigned int packh2(float x, float y) {
    union { half2_t h; unsigned int u; } c;
    c.h = half2_t{(half_t)x, (half_t)y};
    return c.u;
}

__device__ __forceinline__ half2_t h2(unsigned int u) {
    union { unsigned int x; half2_t h; } c;
    c.x = u;
    return c.h;
}

union F4H { float4 f; half2_t h[4]; };
union F2H { float2 f; half2_t h[2]; };

__device__ __forceinline__ float tanh_fast(float p) {
    float ex = __expf(2.0f * p);
    return 1.0f - 2.0f / (ex + 1.0f);
}

// LDS layout (bytes):
//      0: D21T4  [16 j4][256 i][4h]  32768
//  32768: BT4    [16 j4][256 i][4h]  32768
//  65536: CT4    [64 j4][ 64 i][4h]  32768
//  98304: D12T4  [64 j4][ 64 i][4h]  32768
// 131072: DT4    [16 j4][ 64 i][4h]   8192
// 139264: x_h    [256] half            512
// 139776: w_h    [256] half            512
// 140288: d_h    [2][64] half          256
// 140544: red_a  [1024] float         4096
// 144640: red_e  [1024] float         4096
// total 148736 B  (<= 160 KiB, 1 block/CU)
#define LDS_TOTAL 148736

__global__
__attribute__((amdgpu_flat_work_group_size(1024, 1024)))
__attribute__((amdgpu_waves_per_eu(4, 4)))
void lure_kernel(const float* __restrict__ d_g, const float* __restrict__ x0_g,
                 const float* __restrict__ A_g, const float* __restrict__ B_g,
                 const float* __restrict__ B2_g, const float* __restrict__ C_g,
                 const float* __restrict__ D_g, const float* __restrict__ D12_g,
                 const float* __restrict__ C2_g, const float* __restrict__ D21_g,
                 float* __restrict__ out)
{
    __shared__ __align__(16) char smem[LDS_TOTAL];
    half_t* D21T = (half_t*)(smem + 0);
    half_t* BT   = (half_t*)(smem + 32768);
    half_t* CT   = (half_t*)(smem + 65536);
    half_t* D12T = (half_t*)(smem + 98304);
    half_t* DT   = (half_t*)(smem + 131072);
    half_t* x_h  = (half_t*)(smem + 139264);
    half_t* w_h  = (half_t*)(smem + 139776);
    half_t* d_h  = (half_t*)(smem + 140288);
    float*  red_a= (float*)(smem + 140544);
    float*  red_e= (float*)(smem + 144640);

    const int t = threadIdx.x;
    const int b = blockIdx.x;
    const int i = t & 255;    // output row for w/x phases
    const int q = t >> 8;     // K-quarter (cols 64q .. 64q+63)
    const int ie = t & 63;    // output row for e phase
    const int sl = t >> 6;    // e-phase K slice (16 slices)

    // ---- one-time: register-resident quarter-row slices of C2, A, B2
    // Each slice: 64 cols = 32 packed half2 = 2x uint16v SSA values.
    uint16v c2v0 = {}, c2v1 = {}, av0 = {}, av1 = {}, b2v0 = {}, b2v1 = {};
    {
        const float4* c2p = (const float4*)(C2_g + i * 256 + q * 64);
#pragma unroll
        for (int u = 0; u < 8; ++u) {
            float4 v = c2p[u];
            c2v0[2*u]   = packh2(v.x, v.y);
            c2v0[2*u+1] = packh2(v.z, v.w);
        }
#pragma unroll
        for (int u = 0; u < 8; ++u) {
            float4 v = c2p[8 + u];
            c2v1[2*u]   = packh2(v.x, v.y);
            c2v1[2*u+1] = packh2(v.z, v.w);
        }
        const float4* ap = (const float4*)(A_g + i * 256 + q * 64);
#pragma unroll
        for (int u = 0; u < 8; ++u) {
            float4 v = ap[u];
            av0[2*u]   = packh2(v.x, v.y);
            av0[2*u+1] = packh2(v.z, v.w);
        }
#pragma unroll
        for (int u = 0; u < 8; ++u) {
            float4 v = ap[8 + u];
            av1[2*u]   = packh2(v.x, v.y);
            av1[2*u+1] = packh2(v.z, v.w);
        }
        const float4* b2p = (const float4*)(B2_g + i * 256 + q * 64);
#pragma unroll
        for (int u = 0; u < 8; ++u) {
            float4 v = b2p[u];
            b2v0[2*u]   = packh2(v.x, v.y);
            b2v0[2*u+1] = packh2(v.z, v.w);
        }
#pragma unroll
        for (int u = 0; u < 8; ++u) {
            float4 v = b2p[8 + u];
            b2v1[2*u]   = packh2(v.x, v.y);
            b2v1[2*u+1] = packh2(v.z, v.w);
        }
    }

    // ---- one-time: LDS transposed-packed small matrices
    for (int e = t; e < 256 * 64; e += 1024) {         // D21 [256][64]
        int r = e >> 6, c = e & 63;
        D21T[((c >> 2) * 256 + r) * 4 + (c & 3)] = (half_t)D21_g[e];
    }
    for (int e = t; e < 256 * 64; e += 1024) {         // B [256][64]
        int r = e >> 6, c = e & 63;
        BT[((c >> 2) * 256 + r) * 4 + (c & 3)] = (half_t)B_g[e];
    }
    for (int e = t; e < 64 * 256; e += 1024) {         // C [64][256]
        int r = e >> 8, c = e & 255;
        CT[((c >> 2) * 64 + r) * 4 + (c & 3)] = (half_t)C_g[e];
    }
    for (int e = t; e < 64 * 256; e += 1024) {         // D12 [64][256]
        int r = e >> 8, c = e & 255;
        D12T[((c >> 2) * 64 + r) * 4 + (c & 3)] = (half_t)D12_g[e];
    }
    for (int e = t; e < 64 * 64; e += 1024) {          // D [64][64]
        int r = e >> 6, c = e & 63;
        DT[((c >> 2) * 64 + r) * 4 + (c & 3)] = (half_t)D_g[e];
    }
    // initial state + d_0
    if (t < 256) x_h[t] = (half_t)x0_g[b * 256 + t];
    if (t >= 320 && t < 384) d_h[t - 320] = (half_t)d_g[(b * NSTEP) * 64 + (t - 320)];
    __syncthreads();

    const float* dpre = d_g + (b * NSTEP + 1) * 64 + (t - 320); // wave 5 prefetch ptr
    const int out_e_base = b * (NSTEP * 64);
    const int out_x_base = 256 * NSTEP * 64 + b * 256;
    const int out_w_base = 256 * NSTEP * 64 + 256 * 256 + b * 256;

    int cur = 0; // d ring slot for d_k (== k & 1)
    for (int k = 0; k <= NSTEP; ++k) {
        const bool live = (k < NSTEP);

        // prefetch d_{k+1} (wave 5)
        float dpf = 0.0f;
        if (k < NSTEP - 1 && t >= 320 && t < 384) dpf = *dpre;

        // ---- R1: w_pre partial (C2·x + D21·d) and A·x partial
        float aC0 = 0.f, aC1 = 0.f, aA0 = 0.f, aA1 = 0.f;
        if (live) {
            const half_t* xs = x_h + (q << 6);
#pragma unroll
            for (int cc = 0; cc < 4; ++cc) {           // cols 0..31 of slice
                F4H xv; xv.f = *(const float4*)(xs + cc * 8);
                aC0 = fdot2(h2(c2v0[4*cc+0]), xv.h[0], aC0);
                aA0 = fdot2(h2(av0 [4*cc+0]), xv.h[0], aA0);
                aC1 = fdot2(h2(c2v0[4*cc+1]), xv.h[1], aC1);
                aA1 = fdot2(h2(av0 [4*cc+1]), xv.h[1], aA1);
                aC0 = fdot2(h2(c2v0[4*cc+2]), xv.h[2], aC0);
                aA0 = fdot2(h2(av0 [4*cc+2]), xv.h[2], aA0);
                aC1 = fdot2(h2(c2v0[4*cc+3]), xv.h[3], aC1);
                aA1 = fdot2(h2(av0 [4*cc+3]), xv.h[3], aA1);
            }
#pragma unroll
            for (int cc = 0; cc < 4; ++cc) {           // cols 32..63 of slice
                F4H xv; xv.f = *(const float4*)(xs + 32 + cc * 8);
                aC0 = fdot2(h2(c2v1[4*cc+0]), xv.h[0], aC0);
                aA0 = fdot2(h2(av1 [4*cc+0]), xv.h[0], aA0);
                aC1 = fdot2(h2(c2v1[4*cc+1]), xv.h[1], aC1);
                aA1 = fdot2(h2(av1 [4*cc+1]), xv.h[1], aA1);
                aC0 = fdot2(h2(c2v1[4*cc+2]), xv.h[2], aC0);
                aA0 = fdot2(h2(av1 [4*cc+2]), xv.h[2], aA0);
                aC1 = fdot2(h2(c2v1[4*cc+3]), xv.h[3], aC1);
                aA1 = fdot2(h2(av1 [4*cc+3]), xv.h[3], aA1);
            }
#pragma unroll
            for (int qq = 0; qq < 4; ++qq) {
                int j4 = (q << 2) + qq;
                F2H m;  m.f  = *(const float2*)(D21T + (j4 * 256 + i) * 4);
                F2H dv; dv.f = *(const float2*)(d_h + cur * 64 + (j4 << 2));
                aC0 = fdot2(m.h[0], dv.h[0], aC0);
                aC1 = fdot2(m.h[1], dv.h[1], aC1);
            }
            red_a[t] = aC0 + aC1;
        }

        // ---- E phase for step k-1: e = C·x_k + D12·w_{k-1} + D·d_{k-1}
        if (k > 0) {
            float aE0 = 0.f, aE1 = 0.f;
#pragma unroll
            for (int qq = 0; qq < 4; ++qq) {
                int j4 = (sl << 2) + qq;
                F2H m;  m.f  = *(const float2*)(CT + (j4 * 64 + ie) * 4);
                F2H xv; xv.f = *(const float2*)(x_h + (j4 << 2));
                aE0 = fdot2(m.h[0], xv.h[0], aE0);
                aE1 = fdot2(m.h[1], xv.h[1], aE1);
            }
#pragma unroll
            for (int qq = 0; qq < 4; ++qq) {
                int j4 = (sl << 2) + qq;
                F2H m;  m.f  = *(const float2*)(D12T + (j4 * 64 + ie) * 4);
                F2H wv; wv.f = *(const float2*)(w_h + (j4 << 2));
                aE0 = fdot2(m.h[0], wv.h[0], aE0);
                aE1 = fdot2(m.h[1], wv.h[1], aE1);
            }
            {
                int j4 = sl;
                F2H m;  m.f  = *(const float2*)(DT + (j4 * 64 + ie) * 4);
                F2H dv; dv.f = *(const float2*)(d_h + (cur ^ 1) * 64 + (j4 << 2));
                aE0 = fdot2(m.h[0], dv.h[0], aE0);
                aE1 = fdot2(m.h[1], dv.h[1], aE1);
            }
            red_e[t] = aE0 + aE1;
        }
        __syncthreads(); // A

        // ---- R2: tanh+w (waves 0-3) | e-reduce+store (wave 4) | d_h fill (wave 5)
        if (t < 256) {
            if (live) {
                float p = red_a[t] + red_a[t + 256] + red_a[t + 512] + red_a[t + 768];
                float wv = tanh_fast(p);
                w_h[t] = (half_t)wv;
                if (k == NSTEP - 1) out[out_w_base + t] = wv;
            }
        } else if (t < 320) {
            if (k > 0) {
                float ev = 0.f;
#pragma unroll
                for (int s = 0; s < 16; ++s) ev += red_e[ie + 64 * s];
                out[out_e_base + (k - 1) * 64 + ie] = ev;
            }
        } else if (t < 384) {
            if (k < NSTEP - 1) d_h[(cur ^ 1) * 64 + (t - 320)] = (half_t)dpf;
        }
        __syncthreads(); // B

        // ---- R3: x' partial (A·x done) + B2·w + B·d
        if (live) {
            float aX0 = aA0, aX1 = aA1;
            const half_t* wsl = w_h + (q << 6);
#pragma unroll
            for (int cc = 0; cc < 4; ++cc) {           // cols 0..31
                F4H wv; wv.f = *(const float4*)(wsl + cc * 8);
                aX0 = fdot2(h2(b2v0[4*cc+0]), wv.h[0], aX0);
                aX1 = fdot2(h2(b2v0[4*cc+1]), wv.h[1], aX1);
                aX0 = fdot2(h2(b2v0[4*cc+2]), wv.h[2], aX0);
                aX1 = fdot2(h2(b2v0[4*cc+3]), wv.h[3], aX1);
            }
#pragma unroll
            for (int cc = 0; cc < 4; ++cc) {           // cols 32..63
                F4H wv; wv.f = *(const float4*)(wsl + 32 + cc * 8);
                aX0 = fdot2(h2(b2v1[4*cc+0]), wv.h[0], aX0);
                aX1 = fdot2(h2(b2v1[4*cc+1]), wv.h[1], aX1);
                aX0 = fdot2(h2(b2v1[4*cc+2]), wv.h[2], aX0);
                aX1 = fdot2(h2(b2v1[4*cc+3]), wv.h[3], aX1);
            }
#pragma unroll
            for (int qq = 0; qq < 4; ++qq) {
                int j4 = (q << 2) + qq;
                F2H m;  m.f  = *(const float2*)(BT + (j4 * 256 + i) * 4);
                F2H dv; dv.f = *(const float2*)(d_h + cur * 64 + (j4 << 2));
                aX0 = fdot2(m.h[0], dv.h[0], aX0);
                aX1 = fdot2(m.h[1], dv.h[1], aX1);
            }
            red_a[t] = aX0 + aX1;
        }
        __syncthreads(); // C

        // ---- R4: x update
        if (live && t < 256) {
            float xv = red_a[t] + red_a[t + 256] + red_a[t + 512] + red_a[t + 768];
            x_h[t] = (half_t)xv;
            if (k == NSTEP - 1) out[out_x_base + t] = xv;
        }
        dpre += 64;
        cur ^= 1;
        __syncthreads(); // D
    }
}

extern "C" void kernel_launch(void* const* d_in, const int* in_sizes, int n_in,
                              void* d_out, int out_size, void* d_ws, size_t ws_size,
                              hipStream_t stream) {
    (void)in_sizes; (void)n_in; (void)out_size; (void)d_ws; (void)ws_size;
    const float* d_  = (const float*)d_in[0];
    const float* x0  = (const float*)d_in[1];
    const float* A   = (const float*)d_in[2];
    const float* B   = (const float*)d_in[3];
    const float* B2  = (const float*)d_in[4];
    const float* C   = (const float*)d_in[5];
    const float* D   = (const float*)d_in[6];
    const float* D12 = (const float*)d_in[7];
    const float* C2  = (const float*)d_in[8];
    const float* D21 = (const float*)d_in[9];
    float* out = (float*)d_out;

    hipLaunchKernelGGL(lure_kernel, dim3(256), dim3(1024), 0, stream,
                       d_, x0, A, B, B2, C, D, D12, C2, D21, out);
}